// Round 2
// baseline (867.354 us; speedup 1.0000x reference)
//
#include <hip/hip_runtime.h>

// CobaLIF SNN forward. B=256, T=1000, F=700, H=256, O=20.
//
// KEY THEOREM (verified by prior-session counters: correction masks always
// empty, absmax 0.0): for t>=1, if z(t-1)=all-ones then v(t) = 30*g_e(t) >=
// 30*rowsum(relu(w_rec)) ~ 270 >> 1, INDEPENDENT of the input drive (which
// only adds >=0). So z == 1 for all t>=1 by induction from z(0), and the
// readout input is constantly csum => voltages are batch-independent.
//   -> spikes: t=0 from exact fp32 drive; t>=1 pure 1.0 fill (262 MB).
//   -> voltages: per-t replay of the 20-channel scalar recurrence
//      (bit-identical fp32 order), broadcast to B.
// Exactness is NOT assumed: per-b flag (any z(0)==0) and global flag
// (min rowsum_e <= 0.04) gate fallback_k, a full sequential per-b recompute.
// With this data all flags are 0.
//
// R9 restructure: 4 launches -> 3. prep_k eliminated (its outputs fed only
// the never-taken fallback, which now derives relu(w_rec)/rowsums/w_out^T
// on the fly; gflag row-sum min computed directly from w_rec in drive0's
// extra block; csum kept as a bit-identical block in drive0). Spike fill
// switched from 63936 one-shot blocks to 8192 grid-stride blocks (~8
// float4/thread) to cut workgroup-dispatch overhead on the 262 MB stream.
// No checked-output arithmetic changed.

#define TT 1000
#define BB 256
#define FF 700
#define HH 256
#define OO 20

#define NB_SPK 8192        // spike-fill blocks (grid-stride)

// ws layout (bytes):
#define WS_CSUM  0         // float csum[OO]: column sums of w_out
#define WS_GFLAG 128       // int: global fallback flag
#define WS_BFLAG 192       // int[BB]: per-batch fallback flags

// Ballot-based active-feature compaction (256-thread blocks).
__device__ __forceinline__ int build_list(const float* __restrict__ xrow,
                                          int tid, int* __restrict__ xact,
                                          int* __restrict__ wcnt) {
    int lane = tid & 63, w = tid >> 6;
    float4 xv = make_float4(0.f, 0.f, 0.f, 0.f);
    if (tid < 175) xv = reinterpret_cast<const float4*>(xrow)[tid];
    unsigned long long b0 = __ballot(xv.x != 0.f);
    unsigned long long b1 = __ballot(xv.y != 0.f);
    unsigned long long b2 = __ballot(xv.z != 0.f);
    unsigned long long b3 = __ballot(xv.w != 0.f);
    int c0 = __popcll(b0), c1 = __popcll(b1), c2 = __popcll(b2), c3 = __popcll(b3);
    if (lane == 0) wcnt[w] = c0 + c1 + c2 + c3;
    __syncthreads();
    int base = 0;
    for (int i = 0; i < w; ++i) base += wcnt[i];
    int ntot = wcnt[0] + wcnt[1] + wcnt[2] + wcnt[3];
    unsigned long long below = (1ull << lane) - 1ull;
    if (xv.x != 0.f) xact[base + __popcll(b0 & below)] = 4 * tid + 0;
    if (xv.y != 0.f) xact[base + c0 + __popcll(b1 & below)] = 4 * tid + 1;
    if (xv.z != 0.f) xact[base + c0 + c1 + __popcll(b2 & below)] = 4 * tid + 2;
    if (xv.w != 0.f) xact[base + c0 + c1 + c2 + __popcll(b3 & below)] = 4 * tid + 3;
    int npad = (ntot + 7) & ~7;
    if (tid < npad - ntot) xact[ntot + tid] = FF;        // padding (guarded out)
    __syncthreads();
    return npad;
}

// blocks 0..255: exact fp32 t=0 drive -> spike row t=0 + per-b fallback flag.
// block 256:     global fallback flag (induction premise: min rowsum_e > 0.04),
//                row sums computed directly from w_rec (margin test, order-free).
// block 257:     csum (bit-identical to the original prep reduction).
__global__ __launch_bounds__(256) void drive0_k(const float* __restrict__ x,
                                                const float* __restrict__ w_in,
                                                const float* __restrict__ w_rec,
                                                const float* __restrict__ w_out,
                                                float* __restrict__ spk0,
                                                int* __restrict__ bflag,
                                                int* __restrict__ gflag,
                                                float* __restrict__ csum) {
    const int b = blockIdx.x, tid = threadIdx.x;
    if (b == BB) {
        // per-wave: 64 rows each; per row, coalesced 64-lane read + shfl tree.
        __shared__ float wmin[4];
        const int w = tid >> 6, l = tid & 63;
        float mn = 1e30f;
        for (int r = 0; r < 64; ++r) {
            const int h = w * 64 + r;
            float se = 0.f;
            #pragma unroll
            for (int c = 0; c < 4; ++c) se += fmaxf(w_rec[h * HH + c * 64 + l], 0.f);
            #pragma unroll
            for (int m = 32; m; m >>= 1) se += __shfl_xor(se, m, 64);
            mn = fminf(mn, se);
        }
        if (l == 0) wmin[w] = mn;
        __syncthreads();
        if (tid == 0) {
            float m2 = fminf(fminf(wmin[0], wmin[1]), fminf(wmin[2], wmin[3]));
            gflag[0] = (m2 <= 0.04f) ? 1 : 0;
        }
        return;
    }
    if (b == BB + 1) {
        const int l = tid;
        if (l < 64) {
            for (int o = 0; o < OO; ++o) {
                float s = 0.f;
                #pragma unroll
                for (int c = 0; c < 4; ++c) s += w_out[o * HH + c * 64 + l];
                #pragma unroll
                for (int m = 32; m; m >>= 1) s += __shfl_xor(s, m, 64);
                if (l == 0) csum[o] = s;
            }
        }
        return;
    }
    __shared__ int xact[712];
    __shared__ int wcnt[4];
    __shared__ int nz;
    if (tid == 0) nz = 0;                    // visible after build_list's sync
    int npad = build_list(x + (size_t)b * TT * FF, tid, xact, wcnt);
    float ie = 0.f;
    for (int k = 0; k < npad; ++k) {
        int f = __builtin_amdgcn_readfirstlane(xact[k]);
        if (f < FF) {
            float w = w_in[tid * FF + f];
            ie += fmaxf(w, 0.f);
        }
    }
    float v0 = 0.5f * (ie * 60.f);           // reference association: DT*C_M_INV*(ge*(E-v))
    float z = (v0 - 1.f > 0.f) ? 1.f : 0.f;
    spk0[b * HH + tid] = z;
    if (z == 0.f) atomicAdd(&nz, 1);
    __syncthreads();
    if (tid == 0) bflag[b] = (nz != 0);
}

// Fused output writer.
// blocks [0, TT):       t = blk. Per-channel replay of the common-voltage scan
//                       up to t (bit-identical fp32 order), broadcast to all
//                       256 batch rows.
// blocks [TT, TT+NB_SPK): spike fill, 1.0f, grid-stride float4 (262 MB).
__global__ __launch_bounds__(256) void fill_k(const float* __restrict__ csum,
                                              float* __restrict__ volt,
                                              float4* __restrict__ spk_t1,
                                              long n4) {
    const int blk = blockIdx.x, tid = threadIdx.x;
    if (blk < TT) {
        __shared__ float sm[OO];
        if (tid < OO) {
            const float cs = csum[tid];
            float vo = 0.f, io = 0.f;
            for (int k = 0; k <= blk; ++k) {
                vo = vo + 0.01f * (io - vo);             // old io (reference order)
                io = 0.98f * io + cs;                    // i_in == csum (all-fire)
            }
            sm[tid] = vo;
        }
        __syncthreads();
        float vv[OO];
        #pragma unroll
        for (int o = 0; o < OO; ++o) vv[o] = sm[o];      // thread-invariant
        float4* p = (float4*)(volt + ((size_t)blk * BB + tid) * OO);
        #pragma unroll
        for (int q = 0; q < 5; ++q)
            p[q] = make_float4(vv[4 * q], vv[4 * q + 1], vv[4 * q + 2], vv[4 * q + 3]);
    } else {
        long i = (long)(blk - TT) * 256 + tid;
        const long stride = (long)NB_SPK * 256;
        const float4 one = make_float4(1.f, 1.f, 1.f, 1.f);
        for (; i < n4; i += stride) spk_t1[i] = one;
    }
}

// Exact sequential recompute for flagged batches only (normally exits at once).
// Self-contained: derives relu(w_rec) terms, row sums, and w_out^T entries
// directly from the raw weights (cold path; coalescing irrelevant).
__global__ __launch_bounds__(256) void fallback_k(
    const float* __restrict__ x, const float* __restrict__ w_in,
    const float* __restrict__ w_rec, const float* __restrict__ w_out,
    const float* __restrict__ csum,
    const int* __restrict__ gflag, const int* __restrict__ bflag,
    float* __restrict__ out) {
    const int b = blockIdx.x, tid = threadIdx.x;
    if ((gflag[0] | bflag[b]) == 0) return;              // uniform early exit

    const int w = tid >> 6, l = tid & 63;
    __shared__ int xact[712];
    __shared__ int wcnt[4];
    __shared__ unsigned long long mbuf[4];

    float* __restrict__ volt = out;                          // [T,B,O]
    float* __restrict__ spk  = out + (size_t)TT * BB * OO;   // [T,B,H]

    // per-thread row sums of relu(+/- w_rec[tid][*]) (uncoalesced, cold path)
    float2 rs;
    {
        float se = 0.f, si = 0.f;
        const float* wr = w_rec + (size_t)tid * HH;
        for (int j = 0; j < HH; ++j) {
            float wv = wr[j];
            se += fmaxf(wv, 0.f);
            si += fmaxf(-wv, 0.f);
        }
        rs = make_float2(se, si);
    }
    const float cs = (tid < OO) ? csum[tid] : 0.f;
    float ge = 0.f, gi = 0.f, v = 0.f, vo = 0.f, io = 0.f;
    unsigned long long mp0 = 0, mp1 = 0, mp2 = 0, mp3 = 0;

    for (int t = 0; t < TT; ++t) {
        int npad = build_list(x + ((size_t)b * TT + t) * FF, tid, xact, wcnt);
        float ie = 0.f, ii = 0.f;
        for (int k = 0; k < npad; ++k) {
            int f = __builtin_amdgcn_readfirstlane(xact[k]);
            if (f < FF) {
                float wv = w_in[tid * FF + f];
                ie += fmaxf(wv, 0.f);
                ii += fmaxf(-wv, 0.f);
            }
        }
        float ce, ci;
        if (t == 0) { ce = rs.x; ci = rs.y; }            // z_prev = 0 exactly
        else {
            ce = 0.f; ci = 0.f;
            if (mp0 | mp1 | mp2 | mp3) {
                unsigned long long mm;
                #pragma unroll
                for (int q = 0; q < 4; ++q) {
                    mm = (q == 0) ? mp0 : (q == 1) ? mp1 : (q == 2) ? mp2 : mp3;
                    while (mm) {
                        int i = __ffsll(mm) - 1; mm &= mm - 1;
                        float wv = w_rec[(size_t)tid * HH + (q * 64 + i)];
                        ce += fmaxf(wv, 0.f); ci += fmaxf(-wv, 0.f);
                    }
                }
            }
        }
        ge = 0.98f * ge + ie + (rs.x - ce);
        gi = 0.99f * gi + ii + (rs.y - ci);
        v = v + 0.5f * (0.25f * (0.f - v) + ge * (60.f - v) + gi * (0.f - v));
        float z = (v - 1.f > 0.f) ? 1.f : 0.f;
        v *= (1.f - z);
        spk[((size_t)t * BB + b) * HH + tid] = z;

        unsigned long long nf = __ballot(z == 0.f);
        if (l == 0) mbuf[w] = nf;
        __syncthreads();
        mp0 = mbuf[0]; mp1 = mbuf[1]; mp2 = mbuf[2]; mp3 = mbuf[3];

        if (tid < OO) {
            float corr = 0.f;
            if (mp0 | mp1 | mp2 | mp3) {
                unsigned long long mm;
                mm = mp0; while (mm) { int i = __ffsll(mm) - 1; mm &= mm - 1; corr += w_out[(size_t)tid * HH + (0*64+i)]; }
                mm = mp1; while (mm) { int i = __ffsll(mm) - 1; mm &= mm - 1; corr += w_out[(size_t)tid * HH + (1*64+i)]; }
                mm = mp2; while (mm) { int i = __ffsll(mm) - 1; mm &= mm - 1; corr += w_out[(size_t)tid * HH + (2*64+i)]; }
                mm = mp3; while (mm) { int i = __ffsll(mm) - 1; mm &= mm - 1; corr += w_out[(size_t)tid * HH + (3*64+i)]; }
            }
            vo = vo + 0.01f * (io - vo);
            io = 0.98f * io + (cs - corr);
            volt[((size_t)t * BB + b) * OO + tid] = vo;
        }
    }
}

extern "C" void kernel_launch(void* const* d_in, const int* in_sizes, int n_in,
                              void* d_out, int out_size, void* d_ws, size_t ws_size,
                              hipStream_t stream) {
    (void)in_sizes; (void)n_in; (void)out_size; (void)ws_size;
    const float* x     = (const float*)d_in[0];
    const float* w_in  = (const float*)d_in[1];
    const float* w_rec = (const float*)d_in[2];
    const float* w_out = (const float*)d_in[3];
    float* out = (float*)d_out;

    char* ws = (char*)d_ws;
    float*  csum  = (float*)(ws + WS_CSUM);
    int*    gflag = (int*)  (ws + WS_GFLAG);
    int*    bflag = (int*)  (ws + WS_BFLAG);

    float* volt = out;                                   // [T,B,O]
    float* spk  = out + (size_t)TT * BB * OO;            // [T,B,H]
    float4* spk_t1 = (float4*)(spk + (size_t)BB * HH);   // t>=1 region (16B-aligned)
    const long n4 = (long)(TT - 1) * BB * HH / 4;        // 16,367,616

    hipLaunchKernelGGL(drive0_k,   dim3(BB + 2),        dim3(256), 0, stream,
                       x, w_in, w_rec, w_out, spk, bflag, gflag, csum);
    hipLaunchKernelGGL(fill_k,     dim3(TT + NB_SPK),   dim3(256), 0, stream,
                       csum, volt, spk_t1, n4);
    hipLaunchKernelGGL(fallback_k, dim3(BB),            dim3(256), 0, stream,
                       x, w_in, w_rec, w_out, csum, gflag, bflag, out);
}

// Round 3
// 860.736 us; speedup vs baseline: 1.0077x; 1.0077x over previous
//
#include <hip/hip_runtime.h>

// CobaLIF SNN forward. B=256, T=1000, F=700, H=256, O=20.
//
// KEY THEOREM (verified by prior-session counters: correction masks always
// empty, absmax 0.0): for t>=1, if z(t-1)=all-ones then v(t) = 30*g_e(t) >=
// 30*rowsum(relu(w_rec)) ~ 270 >> 1, INDEPENDENT of the input drive (which
// only adds >=0). So z == 1 for all t>=1 by induction from z(0), and the
// readout input is constantly csum => voltages are batch-independent.
//   -> spikes: t=0 from exact fp32 drive; t>=1 pure 1.0 fill (262 MB).
//   -> voltages: per-t replay of the 20-channel scalar recurrence
//      (bit-identical fp32 order), broadcast to B.
// Exactness is NOT assumed: per-b flag (any z(0)==0) and global flag
// (min rowsum_e <= 0.04) gate fallback_k, a full sequential per-b recompute.
// With this data all flags are 0.
//
// R10 deconfound: R9 changed two things at once and regressed +11 us vs R8
// (bench noise floor is ~±2 us, so that was real). This round keeps R9's
// 3-launch structure (prep folded into drive0) and reverts the spike fill
// to R8's one-shot form (one float4 store per thread, 63,936 blocks, zero
// loop overhead, 4x the wave parallelism of the 8192-block grid-stride
// version). Single-variable change; no checked-output arithmetic touched.

#define TT 1000
#define BB 256
#define FF 700
#define HH 256
#define OO 20

// ws layout (bytes):
#define WS_CSUM  0         // float csum[OO]: column sums of w_out
#define WS_GFLAG 128       // int: global fallback flag
#define WS_BFLAG 192       // int[BB]: per-batch fallback flags

// Ballot-based active-feature compaction (256-thread blocks).
__device__ __forceinline__ int build_list(const float* __restrict__ xrow,
                                          int tid, int* __restrict__ xact,
                                          int* __restrict__ wcnt) {
    int lane = tid & 63, w = tid >> 6;
    float4 xv = make_float4(0.f, 0.f, 0.f, 0.f);
    if (tid < 175) xv = reinterpret_cast<const float4*>(xrow)[tid];
    unsigned long long b0 = __ballot(xv.x != 0.f);
    unsigned long long b1 = __ballot(xv.y != 0.f);
    unsigned long long b2 = __ballot(xv.z != 0.f);
    unsigned long long b3 = __ballot(xv.w != 0.f);
    int c0 = __popcll(b0), c1 = __popcll(b1), c2 = __popcll(b2), c3 = __popcll(b3);
    if (lane == 0) wcnt[w] = c0 + c1 + c2 + c3;
    __syncthreads();
    int base = 0;
    for (int i = 0; i < w; ++i) base += wcnt[i];
    int ntot = wcnt[0] + wcnt[1] + wcnt[2] + wcnt[3];
    unsigned long long below = (1ull << lane) - 1ull;
    if (xv.x != 0.f) xact[base + __popcll(b0 & below)] = 4 * tid + 0;
    if (xv.y != 0.f) xact[base + c0 + __popcll(b1 & below)] = 4 * tid + 1;
    if (xv.z != 0.f) xact[base + c0 + c1 + __popcll(b2 & below)] = 4 * tid + 2;
    if (xv.w != 0.f) xact[base + c0 + c1 + c2 + __popcll(b3 & below)] = 4 * tid + 3;
    int npad = (ntot + 7) & ~7;
    if (tid < npad - ntot) xact[ntot + tid] = FF;        // padding (guarded out)
    __syncthreads();
    return npad;
}

// blocks 0..255: exact fp32 t=0 drive -> spike row t=0 + per-b fallback flag.
// block 256:     global fallback flag (induction premise: min rowsum_e > 0.04),
//                row sums computed directly from w_rec (margin test, order-free).
// block 257:     csum (bit-identical to the original prep reduction).
__global__ __launch_bounds__(256) void drive0_k(const float* __restrict__ x,
                                                const float* __restrict__ w_in,
                                                const float* __restrict__ w_rec,
                                                const float* __restrict__ w_out,
                                                float* __restrict__ spk0,
                                                int* __restrict__ bflag,
                                                int* __restrict__ gflag,
                                                float* __restrict__ csum) {
    const int b = blockIdx.x, tid = threadIdx.x;
    if (b == BB) {
        // per-wave: 64 rows each; per row, coalesced 64-lane read + shfl tree.
        __shared__ float wmin[4];
        const int w = tid >> 6, l = tid & 63;
        float mn = 1e30f;
        for (int r = 0; r < 64; ++r) {
            const int h = w * 64 + r;
            float se = 0.f;
            #pragma unroll
            for (int c = 0; c < 4; ++c) se += fmaxf(w_rec[h * HH + c * 64 + l], 0.f);
            #pragma unroll
            for (int m = 32; m; m >>= 1) se += __shfl_xor(se, m, 64);
            mn = fminf(mn, se);
        }
        if (l == 0) wmin[w] = mn;
        __syncthreads();
        if (tid == 0) {
            float m2 = fminf(fminf(wmin[0], wmin[1]), fminf(wmin[2], wmin[3]));
            gflag[0] = (m2 <= 0.04f) ? 1 : 0;
        }
        return;
    }
    if (b == BB + 1) {
        const int l = tid;
        if (l < 64) {
            for (int o = 0; o < OO; ++o) {
                float s = 0.f;
                #pragma unroll
                for (int c = 0; c < 4; ++c) s += w_out[o * HH + c * 64 + l];
                #pragma unroll
                for (int m = 32; m; m >>= 1) s += __shfl_xor(s, m, 64);
                if (l == 0) csum[o] = s;
            }
        }
        return;
    }
    __shared__ int xact[712];
    __shared__ int wcnt[4];
    __shared__ int nz;
    if (tid == 0) nz = 0;                    // visible after build_list's sync
    int npad = build_list(x + (size_t)b * TT * FF, tid, xact, wcnt);
    float ie = 0.f;
    for (int k = 0; k < npad; ++k) {
        int f = __builtin_amdgcn_readfirstlane(xact[k]);
        if (f < FF) {
            float w = w_in[tid * FF + f];
            ie += fmaxf(w, 0.f);
        }
    }
    float v0 = 0.5f * (ie * 60.f);           // reference association: DT*C_M_INV*(ge*(E-v))
    float z = (v0 - 1.f > 0.f) ? 1.f : 0.f;
    spk0[b * HH + tid] = z;
    if (z == 0.f) atomicAdd(&nz, 1);
    __syncthreads();
    if (tid == 0) bflag[b] = (nz != 0);
}

// Fused output writer.
// blocks [0, TT):   t = blk. Per-channel replay of the common-voltage scan up
//                   to t (bit-identical fp32 order to the reference scan), then
//                   broadcast the 20 values to all 256 batch rows.
// blocks [TT, ...): spike fill, 1.0f, one float4 per thread (262 MB coalesced,
//                   one-shot: zero loop overhead, max wave parallelism).
__global__ __launch_bounds__(256) void fill_k(const float* __restrict__ csum,
                                              float* __restrict__ volt,
                                              float4* __restrict__ spk_t1) {
    const int blk = blockIdx.x, tid = threadIdx.x;
    if (blk < TT) {
        __shared__ float sm[OO];
        if (tid < OO) {
            const float cs = csum[tid];
            float vo = 0.f, io = 0.f;
            for (int k = 0; k <= blk; ++k) {
                vo = vo + 0.01f * (io - vo);             // old io (reference order)
                io = 0.98f * io + cs;                    // i_in == csum (all-fire)
            }
            sm[tid] = vo;
        }
        __syncthreads();
        float vv[OO];
        #pragma unroll
        for (int o = 0; o < OO; ++o) vv[o] = sm[o];      // thread-invariant
        float4* p = (float4*)(volt + ((size_t)blk * BB + tid) * OO);
        #pragma unroll
        for (int q = 0; q < 5; ++q)
            p[q] = make_float4(vv[4 * q], vv[4 * q + 1], vv[4 * q + 2], vv[4 * q + 3]);
    } else {
        long i = (long)(blk - TT) * 256 + tid;
        spk_t1[i] = make_float4(1.f, 1.f, 1.f, 1.f);
    }
}

// Exact sequential recompute for flagged batches only (normally exits at once).
// Self-contained: derives relu(w_rec) terms, row sums, and w_out^T entries
// directly from the raw weights (cold path; coalescing irrelevant).
__global__ __launch_bounds__(256) void fallback_k(
    const float* __restrict__ x, const float* __restrict__ w_in,
    const float* __restrict__ w_rec, const float* __restrict__ w_out,
    const float* __restrict__ csum,
    const int* __restrict__ gflag, const int* __restrict__ bflag,
    float* __restrict__ out) {
    const int b = blockIdx.x, tid = threadIdx.x;
    if ((gflag[0] | bflag[b]) == 0) return;              // uniform early exit

    const int w = tid >> 6, l = tid & 63;
    __shared__ int xact[712];
    __shared__ int wcnt[4];
    __shared__ unsigned long long mbuf[4];

    float* __restrict__ volt = out;                          // [T,B,O]
    float* __restrict__ spk  = out + (size_t)TT * BB * OO;   // [T,B,H]

    // per-thread row sums of relu(+/- w_rec[tid][*]) (uncoalesced, cold path)
    float2 rs;
    {
        float se = 0.f, si = 0.f;
        const float* wr = w_rec + (size_t)tid * HH;
        for (int j = 0; j < HH; ++j) {
            float wv = wr[j];
            se += fmaxf(wv, 0.f);
            si += fmaxf(-wv, 0.f);
        }
        rs = make_float2(se, si);
    }
    const float cs = (tid < OO) ? csum[tid] : 0.f;
    float ge = 0.f, gi = 0.f, v = 0.f, vo = 0.f, io = 0.f;
    unsigned long long mp0 = 0, mp1 = 0, mp2 = 0, mp3 = 0;

    for (int t = 0; t < TT; ++t) {
        int npad = build_list(x + ((size_t)b * TT + t) * FF, tid, xact, wcnt);
        float ie = 0.f, ii = 0.f;
        for (int k = 0; k < npad; ++k) {
            int f = __builtin_amdgcn_readfirstlane(xact[k]);
            if (f < FF) {
                float wv = w_in[tid * FF + f];
                ie += fmaxf(wv, 0.f);
                ii += fmaxf(-wv, 0.f);
            }
        }
        float ce, ci;
        if (t == 0) { ce = rs.x; ci = rs.y; }            // z_prev = 0 exactly
        else {
            ce = 0.f; ci = 0.f;
            if (mp0 | mp1 | mp2 | mp3) {
                unsigned long long mm;
                #pragma unroll
                for (int q = 0; q < 4; ++q) {
                    mm = (q == 0) ? mp0 : (q == 1) ? mp1 : (q == 2) ? mp2 : mp3;
                    while (mm) {
                        int i = __ffsll(mm) - 1; mm &= mm - 1;
                        float wv = w_rec[(size_t)tid * HH + (q * 64 + i)];
                        ce += fmaxf(wv, 0.f); ci += fmaxf(-wv, 0.f);
                    }
                }
            }
        }
        ge = 0.98f * ge + ie + (rs.x - ce);
        gi = 0.99f * gi + ii + (rs.y - ci);
        v = v + 0.5f * (0.25f * (0.f - v) + ge * (60.f - v) + gi * (0.f - v));
        float z = (v - 1.f > 0.f) ? 1.f : 0.f;
        v *= (1.f - z);
        spk[((size_t)t * BB + b) * HH + tid] = z;

        unsigned long long nf = __ballot(z == 0.f);
        if (l == 0) mbuf[w] = nf;
        __syncthreads();
        mp0 = mbuf[0]; mp1 = mbuf[1]; mp2 = mbuf[2]; mp3 = mbuf[3];

        if (tid < OO) {
            float corr = 0.f;
            if (mp0 | mp1 | mp2 | mp3) {
                unsigned long long mm;
                mm = mp0; while (mm) { int i = __ffsll(mm) - 1; mm &= mm - 1; corr += w_out[(size_t)tid * HH + (0*64+i)]; }
                mm = mp1; while (mm) { int i = __ffsll(mm) - 1; mm &= mm - 1; corr += w_out[(size_t)tid * HH + (1*64+i)]; }
                mm = mp2; while (mm) { int i = __ffsll(mm) - 1; mm &= mm - 1; corr += w_out[(size_t)tid * HH + (2*64+i)]; }
                mm = mp3; while (mm) { int i = __ffsll(mm) - 1; mm &= mm - 1; corr += w_out[(size_t)tid * HH + (3*64+i)]; }
            }
            vo = vo + 0.01f * (io - vo);
            io = 0.98f * io + (cs - corr);
            volt[((size_t)t * BB + b) * OO + tid] = vo;
        }
    }
}

extern "C" void kernel_launch(void* const* d_in, const int* in_sizes, int n_in,
                              void* d_out, int out_size, void* d_ws, size_t ws_size,
                              hipStream_t stream) {
    (void)in_sizes; (void)n_in; (void)out_size; (void)ws_size;
    const float* x     = (const float*)d_in[0];
    const float* w_in  = (const float*)d_in[1];
    const float* w_rec = (const float*)d_in[2];
    const float* w_out = (const float*)d_in[3];
    float* out = (float*)d_out;

    char* ws = (char*)d_ws;
    float*  csum  = (float*)(ws + WS_CSUM);
    int*    gflag = (int*)  (ws + WS_GFLAG);
    int*    bflag = (int*)  (ws + WS_BFLAG);

    float* volt = out;                                   // [T,B,O]
    float* spk  = out + (size_t)TT * BB * OO;            // [T,B,H]
    float4* spk_t1 = (float4*)(spk + (size_t)BB * HH);   // t>=1 region (16B-aligned)
    const long nblk_spk = (long)(TT - 1) * BB * HH / 4 / 256;   // 63936, exact

    hipLaunchKernelGGL(drive0_k,   dim3(BB + 2),             dim3(256), 0, stream,
                       x, w_in, w_rec, w_out, spk, bflag, gflag, csum);
    hipLaunchKernelGGL(fill_k,     dim3(TT + (int)nblk_spk), dim3(256), 0, stream,
                       csum, volt, spk_t1);
    hipLaunchKernelGGL(fallback_k, dim3(BB),                 dim3(256), 0, stream,
                       x, w_in, w_rec, w_out, csum, gflag, bflag, out);
}

// Round 4
// 847.861 us; speedup vs baseline: 1.0230x; 1.0152x over previous
//
#include <hip/hip_runtime.h>

// CobaLIF SNN forward. B=256, T=1000, F=700, H=256, O=20.
//
// KEY THEOREM (verified by prior-session counters: correction masks always
// empty, absmax 0.0): for t>=1, if z(t-1)=all-ones then v(t) = 30*g_e(t) >=
// 30*rowsum(relu(w_rec)) ~ 270 >> 1, INDEPENDENT of the input drive (which
// only adds >=0). So z == 1 for all t>=1 by induction from z(0), and the
// readout input is constantly csum => voltages are batch-independent.
//   -> spikes: t=0 from exact fp32 drive; t>=1 pure 1.0 fill (262 MB).
//   -> voltages: per-t replay of the 20-channel scalar recurrence
//      (bit-identical fp32 order), broadcast to B.
// Exactness is NOT assumed: per-b flag (any z(0)==0) and global flag
// (min rowsum_e <= 0.04) gate fallback_k, a full sequential per-b recompute.
// With this data all flags are 0.
//
// R11: R10 post-mortem showed the prep-fold's cost: the 256KB w_rec row-sum
// (gflag) became ONE serial block on drive0's critical path (~15-25 us of
// dependent load->shfl latency), blocking fill_k's launch. Fixes:
//  (a) gflag block moved into fill_k's grid (block 0) — it's consumed only
//      by fallback_k, so it only needs to finish before fill_k RETIRES;
//      its latency hides under the 262 MB spike-fill stream. +unroll for MLP.
//  (b) csum parallelized across the 4 waves of its block (5 rows/wave,
//      unrolled; per-row reduction order bit-identical, only the wave->row
//      assignment changed).
// No checked-output arithmetic changed.

#define TT 1000
#define BB 256
#define FF 700
#define HH 256
#define OO 20

// ws layout (bytes):
#define WS_CSUM  0         // float csum[OO]: column sums of w_out
#define WS_GFLAG 128       // int: global fallback flag
#define WS_BFLAG 192       // int[BB]: per-batch fallback flags

// Ballot-based active-feature compaction (256-thread blocks).
__device__ __forceinline__ int build_list(const float* __restrict__ xrow,
                                          int tid, int* __restrict__ xact,
                                          int* __restrict__ wcnt) {
    int lane = tid & 63, w = tid >> 6;
    float4 xv = make_float4(0.f, 0.f, 0.f, 0.f);
    if (tid < 175) xv = reinterpret_cast<const float4*>(xrow)[tid];
    unsigned long long b0 = __ballot(xv.x != 0.f);
    unsigned long long b1 = __ballot(xv.y != 0.f);
    unsigned long long b2 = __ballot(xv.z != 0.f);
    unsigned long long b3 = __ballot(xv.w != 0.f);
    int c0 = __popcll(b0), c1 = __popcll(b1), c2 = __popcll(b2), c3 = __popcll(b3);
    if (lane == 0) wcnt[w] = c0 + c1 + c2 + c3;
    __syncthreads();
    int base = 0;
    for (int i = 0; i < w; ++i) base += wcnt[i];
    int ntot = wcnt[0] + wcnt[1] + wcnt[2] + wcnt[3];
    unsigned long long below = (1ull << lane) - 1ull;
    if (xv.x != 0.f) xact[base + __popcll(b0 & below)] = 4 * tid + 0;
    if (xv.y != 0.f) xact[base + c0 + __popcll(b1 & below)] = 4 * tid + 1;
    if (xv.z != 0.f) xact[base + c0 + c1 + __popcll(b2 & below)] = 4 * tid + 2;
    if (xv.w != 0.f) xact[base + c0 + c1 + c2 + __popcll(b3 & below)] = 4 * tid + 3;
    int npad = (ntot + 7) & ~7;
    if (tid < npad - ntot) xact[ntot + tid] = FF;        // padding (guarded out)
    __syncthreads();
    return npad;
}

// blocks 0..255: exact fp32 t=0 drive -> spike row t=0 + per-b fallback flag.
// block 256:     csum; wave w reduces rows 5w..5w+4 (per-row order bit-identical
//                to the original: 4 strided chunk adds per lane + shfl-xor tree).
__global__ __launch_bounds__(256) void drive0_k(const float* __restrict__ x,
                                                const float* __restrict__ w_in,
                                                const float* __restrict__ w_out,
                                                float* __restrict__ spk0,
                                                int* __restrict__ bflag,
                                                float* __restrict__ csum) {
    const int b = blockIdx.x, tid = threadIdx.x;
    if (b == BB) {
        const int w = tid >> 6, l = tid & 63;
        #pragma unroll
        for (int q = 0; q < 5; ++q) {
            const int o = w * 5 + q;
            float s = 0.f;
            #pragma unroll
            for (int c = 0; c < 4; ++c) s += w_out[o * HH + c * 64 + l];
            #pragma unroll
            for (int m = 32; m; m >>= 1) s += __shfl_xor(s, m, 64);
            if (l == 0) csum[o] = s;
        }
        return;
    }
    __shared__ int xact[712];
    __shared__ int wcnt[4];
    __shared__ int nz;
    if (tid == 0) nz = 0;                    // visible after build_list's sync
    int npad = build_list(x + (size_t)b * TT * FF, tid, xact, wcnt);
    float ie = 0.f;
    for (int k = 0; k < npad; ++k) {
        int f = __builtin_amdgcn_readfirstlane(xact[k]);
        if (f < FF) {
            float w = w_in[tid * FF + f];
            ie += fmaxf(w, 0.f);
        }
    }
    float v0 = 0.5f * (ie * 60.f);           // reference association: DT*C_M_INV*(ge*(E-v))
    float z = (v0 - 1.f > 0.f) ? 1.f : 0.f;
    spk0[b * HH + tid] = z;
    if (z == 0.f) atomicAdd(&nz, 1);
    __syncthreads();
    if (tid == 0) bflag[b] = (nz != 0);
}

// Fused output writer.
// block 0:            global fallback flag (induction premise: min rowsum_e >
//                     0.04) from raw w_rec. Consumed only by fallback_k (next
//                     kernel), so its latency hides under the spike fill.
// blocks [1, TT]:     t = blk-1. Per-channel replay of the common-voltage scan
//                     (bit-identical fp32 order), broadcast to 256 batch rows.
// blocks (TT, ...]:   spike fill, 1.0f, one float4 per thread (262 MB).
__global__ __launch_bounds__(256) void fill_k(const float* __restrict__ csum,
                                              const float* __restrict__ w_rec,
                                              float* __restrict__ volt,
                                              float4* __restrict__ spk_t1,
                                              int* __restrict__ gflag) {
    const int blk = blockIdx.x, tid = threadIdx.x;
    if (blk == 0) {
        __shared__ float wmin[4];
        const int w = tid >> 6, l = tid & 63;
        float mn = 1e30f;
        #pragma unroll 4
        for (int r = 0; r < 64; ++r) {
            const int h = w * 64 + r;
            float se = 0.f;
            #pragma unroll
            for (int c = 0; c < 4; ++c) se += fmaxf(w_rec[h * HH + c * 64 + l], 0.f);
            #pragma unroll
            for (int m = 32; m; m >>= 1) se += __shfl_xor(se, m, 64);
            mn = fminf(mn, se);
        }
        if (l == 0) wmin[w] = mn;
        __syncthreads();
        if (tid == 0) {
            float m2 = fminf(fminf(wmin[0], wmin[1]), fminf(wmin[2], wmin[3]));
            gflag[0] = (m2 <= 0.04f) ? 1 : 0;
        }
        return;
    }
    if (blk <= TT) {
        const int t = blk - 1;
        __shared__ float sm[OO];
        if (tid < OO) {
            const float cs = csum[tid];
            float vo = 0.f, io = 0.f;
            for (int k = 0; k <= t; ++k) {
                vo = vo + 0.01f * (io - vo);             // old io (reference order)
                io = 0.98f * io + cs;                    // i_in == csum (all-fire)
            }
            sm[tid] = vo;
        }
        __syncthreads();
        float vv[OO];
        #pragma unroll
        for (int o = 0; o < OO; ++o) vv[o] = sm[o];      // thread-invariant
        float4* p = (float4*)(volt + ((size_t)t * BB + tid) * OO);
        #pragma unroll
        for (int q = 0; q < 5; ++q)
            p[q] = make_float4(vv[4 * q], vv[4 * q + 1], vv[4 * q + 2], vv[4 * q + 3]);
    } else {
        long i = (long)(blk - TT - 1) * 256 + tid;
        spk_t1[i] = make_float4(1.f, 1.f, 1.f, 1.f);
    }
}

// Exact sequential recompute for flagged batches only (normally exits at once).
// Self-contained: derives relu(w_rec) terms, row sums, and w_out^T entries
// directly from the raw weights (cold path; coalescing irrelevant).
__global__ __launch_bounds__(256) void fallback_k(
    const float* __restrict__ x, const float* __restrict__ w_in,
    const float* __restrict__ w_rec, const float* __restrict__ w_out,
    const float* __restrict__ csum,
    const int* __restrict__ gflag, const int* __restrict__ bflag,
    float* __restrict__ out) {
    const int b = blockIdx.x, tid = threadIdx.x;
    if ((gflag[0] | bflag[b]) == 0) return;              // uniform early exit

    const int w = tid >> 6, l = tid & 63;
    __shared__ int xact[712];
    __shared__ int wcnt[4];
    __shared__ unsigned long long mbuf[4];

    float* __restrict__ volt = out;                          // [T,B,O]
    float* __restrict__ spk  = out + (size_t)TT * BB * OO;   // [T,B,H]

    // per-thread row sums of relu(+/- w_rec[tid][*]) (uncoalesced, cold path)
    float2 rs;
    {
        float se = 0.f, si = 0.f;
        const float* wr = w_rec + (size_t)tid * HH;
        for (int j = 0; j < HH; ++j) {
            float wv = wr[j];
            se += fmaxf(wv, 0.f);
            si += fmaxf(-wv, 0.f);
        }
        rs = make_float2(se, si);
    }
    const float cs = (tid < OO) ? csum[tid] : 0.f;
    float ge = 0.f, gi = 0.f, v = 0.f, vo = 0.f, io = 0.f;
    unsigned long long mp0 = 0, mp1 = 0, mp2 = 0, mp3 = 0;

    for (int t = 0; t < TT; ++t) {
        int npad = build_list(x + ((size_t)b * TT + t) * FF, tid, xact, wcnt);
        float ie = 0.f, ii = 0.f;
        for (int k = 0; k < npad; ++k) {
            int f = __builtin_amdgcn_readfirstlane(xact[k]);
            if (f < FF) {
                float wv = w_in[tid * FF + f];
                ie += fmaxf(wv, 0.f);
                ii += fmaxf(-wv, 0.f);
            }
        }
        float ce, ci;
        if (t == 0) { ce = rs.x; ci = rs.y; }            // z_prev = 0 exactly
        else {
            ce = 0.f; ci = 0.f;
            if (mp0 | mp1 | mp2 | mp3) {
                unsigned long long mm;
                #pragma unroll
                for (int q = 0; q < 4; ++q) {
                    mm = (q == 0) ? mp0 : (q == 1) ? mp1 : (q == 2) ? mp2 : mp3;
                    while (mm) {
                        int i = __ffsll(mm) - 1; mm &= mm - 1;
                        float wv = w_rec[(size_t)tid * HH + (q * 64 + i)];
                        ce += fmaxf(wv, 0.f); ci += fmaxf(-wv, 0.f);
                    }
                }
            }
        }
        ge = 0.98f * ge + ie + (rs.x - ce);
        gi = 0.99f * gi + ii + (rs.y - ci);
        v = v + 0.5f * (0.25f * (0.f - v) + ge * (60.f - v) + gi * (0.f - v));
        float z = (v - 1.f > 0.f) ? 1.f : 0.f;
        v *= (1.f - z);
        spk[((size_t)t * BB + b) * HH + tid] = z;

        unsigned long long nf = __ballot(z == 0.f);
        if (l == 0) mbuf[w] = nf;
        __syncthreads();
        mp0 = mbuf[0]; mp1 = mbuf[1]; mp2 = mbuf[2]; mp3 = mbuf[3];

        if (tid < OO) {
            float corr = 0.f;
            if (mp0 | mp1 | mp2 | mp3) {
                unsigned long long mm;
                mm = mp0; while (mm) { int i = __ffsll(mm) - 1; mm &= mm - 1; corr += w_out[(size_t)tid * HH + (0*64+i)]; }
                mm = mp1; while (mm) { int i = __ffsll(mm) - 1; mm &= mm - 1; corr += w_out[(size_t)tid * HH + (1*64+i)]; }
                mm = mp2; while (mm) { int i = __ffsll(mm) - 1; mm &= mm - 1; corr += w_out[(size_t)tid * HH + (2*64+i)]; }
                mm = mp3; while (mm) { int i = __ffsll(mm) - 1; mm &= mm - 1; corr += w_out[(size_t)tid * HH + (3*64+i)]; }
            }
            vo = vo + 0.01f * (io - vo);
            io = 0.98f * io + (cs - corr);
            volt[((size_t)t * BB + b) * OO + tid] = vo;
        }
    }
}

extern "C" void kernel_launch(void* const* d_in, const int* in_sizes, int n_in,
                              void* d_out, int out_size, void* d_ws, size_t ws_size,
                              hipStream_t stream) {
    (void)in_sizes; (void)n_in; (void)out_size; (void)ws_size;
    const float* x     = (const float*)d_in[0];
    const float* w_in  = (const float*)d_in[1];
    const float* w_rec = (const float*)d_in[2];
    const float* w_out = (const float*)d_in[3];
    float* out = (float*)d_out;

    char* ws = (char*)d_ws;
    float*  csum  = (float*)(ws + WS_CSUM);
    int*    gflag = (int*)  (ws + WS_GFLAG);
    int*    bflag = (int*)  (ws + WS_BFLAG);

    float* volt = out;                                   // [T,B,O]
    float* spk  = out + (size_t)TT * BB * OO;            // [T,B,H]
    float4* spk_t1 = (float4*)(spk + (size_t)BB * HH);   // t>=1 region (16B-aligned)
    const long nblk_spk = (long)(TT - 1) * BB * HH / 4 / 256;   // 63936, exact

    hipLaunchKernelGGL(drive0_k,   dim3(BB + 1),                 dim3(256), 0, stream,
                       x, w_in, w_out, spk, bflag, csum);
    hipLaunchKernelGGL(fill_k,     dim3(1 + TT + (int)nblk_spk), dim3(256), 0, stream,
                       csum, w_rec, volt, spk_t1, gflag);
    hipLaunchKernelGGL(fallback_k, dim3(BB),                     dim3(256), 0, stream,
                       x, w_in, w_rec, w_out, csum, gflag, bflag, out);
}

// Round 5
// 845.958 us; speedup vs baseline: 1.0253x; 1.0022x over previous
//
#include <hip/hip_runtime.h>

// CobaLIF SNN forward. B=256, T=1000, F=700, H=256, O=20.
//
// KEY THEOREM (verified by prior-session counters: correction masks always
// empty, absmax 0.0): for t>=1, if z(t-1)=all-ones then v(t) = 30*g_e(t) >=
// 30*rowsum(relu(w_rec)) ~ 270 >> 1, INDEPENDENT of the input drive (which
// only adds >=0). So z == 1 for all t>=1 by induction from z(0), and the
// readout input is constantly csum => voltages are batch-independent.
//   -> spikes: t=0 from exact fp32 drive; t>=1 pure 1.0 fill (262 MB).
//   -> voltages: per-t replay of the 20-channel scalar recurrence
//      (bit-identical fp32 order), broadcast to B.
// Exactness is NOT assumed: per-b flag (any z(0)==0) and global flag
// (min rowsum_e <= 0.04) gate fallback_k, a full sequential per-b recompute.
// With this data all flags are 0.
//
// R12: 3 launches -> 2. The only drive0->fill data dep was csum (20 floats);
// volt blocks now recompute it bit-identically from w_out themselves (20 KB,
// L2-resident, hidden under the store stream), so drive0/gflag/volt/spike-fill
// merge into ONE kernel with disjoint write-sets and zero intra-launch deps.
// Drive + gflag + volt blocks are dispatched first and their latency hides
// under the 63,936-block fill tail. fallback_k stays a separate launch (it
// overwrites fill output when triggered, so it must not run concurrently);
// it self-computes csum on its cold path. No checked-output arithmetic
// changed anywhere.

#define TT 1000
#define BB 256
#define FF 700
#define HH 256
#define OO 20

#define BLK_GFLAG 256          // mega grid: [0,256) drive, 256 gflag,
#define BLK_VOLT0 257          // [257, 257+TT) volt, [257+TT, ...) spike fill
#define NBLK_SPK  63936        // (TT-1)*BB*HH/4/256, exact

// ws layout (bytes):
#define WS_GFLAG 0             // int: global fallback flag
#define WS_BFLAG 64            // int[BB]: per-batch fallback flags

// Ballot-based active-feature compaction (256-thread blocks).
__device__ __forceinline__ int build_list(const float* __restrict__ xrow,
                                          int tid, int* __restrict__ xact,
                                          int* __restrict__ wcnt) {
    int lane = tid & 63, w = tid >> 6;
    float4 xv = make_float4(0.f, 0.f, 0.f, 0.f);
    if (tid < 175) xv = reinterpret_cast<const float4*>(xrow)[tid];
    unsigned long long b0 = __ballot(xv.x != 0.f);
    unsigned long long b1 = __ballot(xv.y != 0.f);
    unsigned long long b2 = __ballot(xv.z != 0.f);
    unsigned long long b3 = __ballot(xv.w != 0.f);
    int c0 = __popcll(b0), c1 = __popcll(b1), c2 = __popcll(b2), c3 = __popcll(b3);
    if (lane == 0) wcnt[w] = c0 + c1 + c2 + c3;
    __syncthreads();
    int base = 0;
    for (int i = 0; i < w; ++i) base += wcnt[i];
    int ntot = wcnt[0] + wcnt[1] + wcnt[2] + wcnt[3];
    unsigned long long below = (1ull << lane) - 1ull;
    if (xv.x != 0.f) xact[base + __popcll(b0 & below)] = 4 * tid + 0;
    if (xv.y != 0.f) xact[base + c0 + __popcll(b1 & below)] = 4 * tid + 1;
    if (xv.z != 0.f) xact[base + c0 + c1 + __popcll(b2 & below)] = 4 * tid + 2;
    if (xv.w != 0.f) xact[base + c0 + c1 + c2 + __popcll(b3 & below)] = 4 * tid + 3;
    int npad = (ntot + 7) & ~7;
    if (tid < npad - ntot) xact[ntot + tid] = FF;        // padding (guarded out)
    __syncthreads();
    return npad;
}

// csum reduction, bit-identical per-row order (4 strided chunk adds per lane +
// shfl-xor tree); wave w handles rows 5w..5w+4. Result broadcast via shared.
__device__ __forceinline__ void csum_to_shared(const float* __restrict__ w_out,
                                               int tid, float* __restrict__ cs_sm) {
    const int w = tid >> 6, l = tid & 63;
    #pragma unroll
    for (int q = 0; q < 5; ++q) {
        const int o = w * 5 + q;
        float s = 0.f;
        #pragma unroll
        for (int c = 0; c < 4; ++c) s += w_out[o * HH + c * 64 + l];
        #pragma unroll
        for (int m = 32; m; m >>= 1) s += __shfl_xor(s, m, 64);
        if (l == 0) cs_sm[o] = s;
    }
    __syncthreads();
}

// Mega-kernel: all write-sets disjoint, no intra-launch data deps.
// blocks [0,256):        b = blk. Exact fp32 t=0 drive -> spike row t=0 +
//                        per-b fallback flag.
// block 256:             global fallback flag (min rowsum_e > 0.04) from w_rec.
// blocks [257, 257+TT):  t = blk-257. Self-compute csum (bit-identical), then
//                        per-channel replay of the common-voltage scan
//                        (bit-identical fp32 order), broadcast to 256 rows.
// blocks [257+TT, ...):  spike fill, 1.0f, one float4 per thread (262 MB).
__global__ __launch_bounds__(256) void mega_k(const float* __restrict__ x,
                                              const float* __restrict__ w_in,
                                              const float* __restrict__ w_rec,
                                              const float* __restrict__ w_out,
                                              float* __restrict__ volt,
                                              float* __restrict__ spk0,
                                              float4* __restrict__ spk_t1,
                                              int* __restrict__ bflag,
                                              int* __restrict__ gflag) {
    const int blk = blockIdx.x, tid = threadIdx.x;

    if (blk < BB) {                                      // ---- drive, b = blk
        const int b = blk;
        __shared__ int xact[712];
        __shared__ int wcnt[4];
        __shared__ int nz;
        if (tid == 0) nz = 0;                // visible after build_list's sync
        int npad = build_list(x + (size_t)b * TT * FF, tid, xact, wcnt);
        float ie = 0.f;
        for (int k = 0; k < npad; ++k) {
            int f = __builtin_amdgcn_readfirstlane(xact[k]);
            if (f < FF) {
                float w = w_in[tid * FF + f];
                ie += fmaxf(w, 0.f);
            }
        }
        float v0 = 0.5f * (ie * 60.f);       // reference association: DT*C_M_INV*(ge*(E-v))
        float z = (v0 - 1.f > 0.f) ? 1.f : 0.f;
        spk0[b * HH + tid] = z;
        if (z == 0.f) atomicAdd(&nz, 1);
        __syncthreads();
        if (tid == 0) bflag[b] = (nz != 0);
        return;
    }

    if (blk == BLK_GFLAG) {                              // ---- global flag
        __shared__ float wmin[4];
        const int w = tid >> 6, l = tid & 63;
        float mn = 1e30f;
        #pragma unroll 4
        for (int r = 0; r < 64; ++r) {
            const int h = w * 64 + r;
            float se = 0.f;
            #pragma unroll
            for (int c = 0; c < 4; ++c) se += fmaxf(w_rec[h * HH + c * 64 + l], 0.f);
            #pragma unroll
            for (int m = 32; m; m >>= 1) se += __shfl_xor(se, m, 64);
            mn = fminf(mn, se);
        }
        if (l == 0) wmin[w] = mn;
        __syncthreads();
        if (tid == 0) {
            float m2 = fminf(fminf(wmin[0], wmin[1]), fminf(wmin[2], wmin[3]));
            gflag[0] = (m2 <= 0.04f) ? 1 : 0;
        }
        return;
    }

    if (blk < BLK_VOLT0 + TT) {                          // ---- volt, t = blk-257
        const int t = blk - BLK_VOLT0;
        __shared__ float cs_sm[OO];
        __shared__ float sm[OO];
        csum_to_shared(w_out, tid, cs_sm);
        if (tid < OO) {
            const float cs = cs_sm[tid];
            float vo = 0.f, io = 0.f;
            for (int k = 0; k <= t; ++k) {
                vo = vo + 0.01f * (io - vo);             // old io (reference order)
                io = 0.98f * io + cs;                    // i_in == csum (all-fire)
            }
            sm[tid] = vo;
        }
        __syncthreads();
        float vv[OO];
        #pragma unroll
        for (int o = 0; o < OO; ++o) vv[o] = sm[o];      // thread-invariant
        float4* p = (float4*)(volt + ((size_t)t * BB + tid) * OO);
        #pragma unroll
        for (int q = 0; q < 5; ++q)
            p[q] = make_float4(vv[4 * q], vv[4 * q + 1], vv[4 * q + 2], vv[4 * q + 3]);
        return;
    }

    // ---- spike fill (one float4 per thread, zero loop overhead)
    long i = (long)(blk - (BLK_VOLT0 + TT)) * 256 + tid;
    spk_t1[i] = make_float4(1.f, 1.f, 1.f, 1.f);
}

// Exact sequential recompute for flagged batches only (normally exits at once).
// Self-contained: derives relu(w_rec) terms, row sums, csum, and w_out^T
// entries directly from the raw weights (cold path; coalescing irrelevant).
__global__ __launch_bounds__(256) void fallback_k(
    const float* __restrict__ x, const float* __restrict__ w_in,
    const float* __restrict__ w_rec, const float* __restrict__ w_out,
    const int* __restrict__ gflag, const int* __restrict__ bflag,
    float* __restrict__ out) {
    const int b = blockIdx.x, tid = threadIdx.x;
    if ((gflag[0] | bflag[b]) == 0) return;              // uniform early exit

    const int w = tid >> 6, l = tid & 63;
    __shared__ int xact[712];
    __shared__ int wcnt[4];
    __shared__ unsigned long long mbuf[4];
    __shared__ float cs_sm[OO];

    float* __restrict__ volt = out;                          // [T,B,O]
    float* __restrict__ spk  = out + (size_t)TT * BB * OO;   // [T,B,H]

    csum_to_shared(w_out, tid, cs_sm);                   // bit-identical csum

    // per-thread row sums of relu(+/- w_rec[tid][*]) (uncoalesced, cold path)
    float2 rs;
    {
        float se = 0.f, si = 0.f;
        const float* wr = w_rec + (size_t)tid * HH;
        for (int j = 0; j < HH; ++j) {
            float wv = wr[j];
            se += fmaxf(wv, 0.f);
            si += fmaxf(-wv, 0.f);
        }
        rs = make_float2(se, si);
    }
    const float cs = (tid < OO) ? cs_sm[tid] : 0.f;
    float ge = 0.f, gi = 0.f, v = 0.f, vo = 0.f, io = 0.f;
    unsigned long long mp0 = 0, mp1 = 0, mp2 = 0, mp3 = 0;

    for (int t = 0; t < TT; ++t) {
        int npad = build_list(x + ((size_t)b * TT + t) * FF, tid, xact, wcnt);
        float ie = 0.f, ii = 0.f;
        for (int k = 0; k < npad; ++k) {
            int f = __builtin_amdgcn_readfirstlane(xact[k]);
            if (f < FF) {
                float wv = w_in[tid * FF + f];
                ie += fmaxf(wv, 0.f);
                ii += fmaxf(-wv, 0.f);
            }
        }
        float ce, ci;
        if (t == 0) { ce = rs.x; ci = rs.y; }            // z_prev = 0 exactly
        else {
            ce = 0.f; ci = 0.f;
            if (mp0 | mp1 | mp2 | mp3) {
                unsigned long long mm;
                #pragma unroll
                for (int q = 0; q < 4; ++q) {
                    mm = (q == 0) ? mp0 : (q == 1) ? mp1 : (q == 2) ? mp2 : mp3;
                    while (mm) {
                        int i = __ffsll(mm) - 1; mm &= mm - 1;
                        float wv = w_rec[(size_t)tid * HH + (q * 64 + i)];
                        ce += fmaxf(wv, 0.f); ci += fmaxf(-wv, 0.f);
                    }
                }
            }
        }
        ge = 0.98f * ge + ie + (rs.x - ce);
        gi = 0.99f * gi + ii + (rs.y - ci);
        v = v + 0.5f * (0.25f * (0.f - v) + ge * (60.f - v) + gi * (0.f - v));
        float z = (v - 1.f > 0.f) ? 1.f : 0.f;
        v *= (1.f - z);
        spk[((size_t)t * BB + b) * HH + tid] = z;

        unsigned long long nf = __ballot(z == 0.f);
        if (l == 0) mbuf[w] = nf;
        __syncthreads();
        mp0 = mbuf[0]; mp1 = mbuf[1]; mp2 = mbuf[2]; mp3 = mbuf[3];

        if (tid < OO) {
            float corr = 0.f;
            if (mp0 | mp1 | mp2 | mp3) {
                unsigned long long mm;
                mm = mp0; while (mm) { int i = __ffsll(mm) - 1; mm &= mm - 1; corr += w_out[(size_t)tid * HH + (0*64+i)]; }
                mm = mp1; while (mm) { int i = __ffsll(mm) - 1; mm &= mm - 1; corr += w_out[(size_t)tid * HH + (1*64+i)]; }
                mm = mp2; while (mm) { int i = __ffsll(mm) - 1; mm &= mm - 1; corr += w_out[(size_t)tid * HH + (2*64+i)]; }
                mm = mp3; while (mm) { int i = __ffsll(mm) - 1; mm &= mm - 1; corr += w_out[(size_t)tid * HH + (3*64+i)]; }
            }
            vo = vo + 0.01f * (io - vo);
            io = 0.98f * io + (cs - corr);
            volt[((size_t)t * BB + b) * OO + tid] = vo;
        }
    }
}

extern "C" void kernel_launch(void* const* d_in, const int* in_sizes, int n_in,
                              void* d_out, int out_size, void* d_ws, size_t ws_size,
                              hipStream_t stream) {
    (void)in_sizes; (void)n_in; (void)out_size; (void)ws_size;
    const float* x     = (const float*)d_in[0];
    const float* w_in  = (const float*)d_in[1];
    const float* w_rec = (const float*)d_in[2];
    const float* w_out = (const float*)d_in[3];
    float* out = (float*)d_out;

    char* ws = (char*)d_ws;
    int* gflag = (int*)(ws + WS_GFLAG);
    int* bflag = (int*)(ws + WS_BFLAG);

    float* volt = out;                                   // [T,B,O]
    float* spk  = out + (size_t)TT * BB * OO;            // [T,B,H]
    float4* spk_t1 = (float4*)(spk + (size_t)BB * HH);   // t>=1 region (16B-aligned)

    hipLaunchKernelGGL(mega_k,     dim3(BLK_VOLT0 + TT + NBLK_SPK), dim3(256), 0, stream,
                       x, w_in, w_rec, w_out, volt, spk, spk_t1, bflag, gflag);
    hipLaunchKernelGGL(fallback_k, dim3(BB),                        dim3(256), 0, stream,
                       x, w_in, w_rec, w_out, gflag, bflag, out);
}